// Round 5
// baseline (425.896 us; speedup 1.0000x reference)
//
#include <hip/hip_runtime.h>
#include <hip/hip_fp16.h>
#include <math.h>

#define L_SIG 65537
#define NH    65536     // half-size complex FFT length (NFFT/2)
#define NSIG  256
#define PI_F  3.14159265358979323846f
#define ZSTR  264       // h2 stride for fused LDS rows (264%32==8 -> <=2-way banks)

struct c32 { float x, y; };
typedef __half2 h2;
__device__ __forceinline__ c32 mkc(float a, float b){ c32 r; r.x=a; r.y=b; return r; }
__device__ __forceinline__ c32 cadd(c32 a, c32 b){ return mkc(a.x+b.x, a.y+b.y); }
__device__ __forceinline__ c32 csub(c32 a, c32 b){ return mkc(a.x-b.x, a.y-b.y); }
__device__ __forceinline__ c32 cmul(c32 a, c32 b){ return mkc(a.x*b.x - a.y*b.y, a.x*b.y + a.y*b.x); }
__device__ __forceinline__ h2  c2h(c32 a){ return __floats2half2_rn(a.x, a.y); }
__device__ __forceinline__ c32 h2c(h2 a){ float2 f = __half22float2(a); return mkc(f.x, f.y); }

// ---------------- 16-point FFT in registers (radix-4 x 2) ------------------
template<int S>
__device__ __forceinline__ void fft16(c32 v[16]) {
  constexpr float C16[16] = {
    1.0f, 0.9238795325112867f, 0.7071067811865476f, 0.3826834323650898f,
    0.0f,-0.3826834323650898f,-0.7071067811865476f,-0.9238795325112867f,
   -1.0f,-0.9238795325112867f,-0.7071067811865476f,-0.3826834323650898f,
    0.0f, 0.3826834323650898f, 0.7071067811865476f, 0.9238795325112867f };
  constexpr float S16[16] = {
    0.0f, 0.3826834323650898f, 0.7071067811865476f, 0.9238795325112867f,
    1.0f, 0.9238795325112867f, 0.7071067811865476f, 0.3826834323650898f,
    0.0f,-0.3826834323650898f,-0.7071067811865476f,-0.9238795325112867f,
   -1.0f,-0.9238795325112867f,-0.7071067811865476f,-0.3826834323650898f };
  c32 s[16];
  #pragma unroll
  for (int b0 = 0; b0 < 4; ++b0) {
    c32 x0=v[b0], x1=v[b0+4], x2=v[b0+8], x3=v[b0+12];
    c32 u0=cadd(x0,x2), u1=csub(x0,x2), u2=cadd(x1,x3), u3=csub(x1,x3);
    c32 iu3 = mkc(-u3.y, u3.x);
    c32 yy[4];
    yy[0]=cadd(u0,u2); yy[2]=csub(u0,u2);
    if (S < 0) { yy[1]=csub(u1,iu3); yy[3]=cadd(u1,iu3); }
    else       { yy[1]=cadd(u1,iu3); yy[3]=csub(u1,iu3); }
    #pragma unroll
    for (int c0 = 0; c0 < 4; ++c0) {
      const int p = (b0*c0) & 15;
      c32 w = mkc(C16[p], (S<0) ? -S16[p] : S16[p]);
      s[c0*4 + b0] = cmul(yy[c0], w);
    }
  }
  #pragma unroll
  for (int c0 = 0; c0 < 4; ++c0) {
    c32 x0=s[c0*4+0], x1=s[c0*4+1], x2=s[c0*4+2], x3=s[c0*4+3];
    c32 u0=cadd(x0,x2), u1=csub(x0,x2), u2=cadd(x1,x3), u3=csub(x1,x3);
    c32 iu3 = mkc(-u3.y, u3.x);
    c32 yy[4];
    yy[0]=cadd(u0,u2); yy[2]=csub(u0,u2);
    if (S < 0) { yy[1]=csub(u1,iu3); yy[3]=cadd(u1,iu3); }
    else       { yy[1]=cadd(u1,iu3); yy[3]=csub(u1,iu3); }
    v[c0+0]=yy[0]; v[c0+4]=yy[1]; v[c0+8]=yy[2]; v[c0+12]=yy[3];
  }
}

// ------------- 256-pt FFT, 16-thread team, SoA + XOR-swizzled LDS ---------
template<int S>
__device__ __forceinline__ void fft256_team(c32 v[16], int r, int t,
                                            float* sre, float* sim) {
  fft16<S>(v);
  float ang = (float)S * (2.0f*PI_F/256.0f) * (float)r;
  c32 st; __sincosf(ang, &st.y, &st.x);
  c32 w = st;
  #pragma unroll
  for (int c = 1; c < 16; ++c) { v[c] = cmul(v[c], w); w = cmul(w, st); }
  __syncthreads();
  #pragma unroll
  for (int c = 0; c < 16; ++c) {
    int idx = c*256 + ((r*16 + t) ^ ((c & 3) << 3));
    sre[idx] = v[c].x; sim[idx] = v[c].y;
  }
  __syncthreads();
  #pragma unroll
  for (int a = 0; a < 16; ++a) {
    int idx = r*256 + ((a*16 + t) ^ ((r & 3) << 3));
    v[a] = mkc(sre[idx], sim[idx]);
  }
  fft16<S>(v);
}

__device__ __forceinline__ int colof(int q, int s) {
  return (s < 10) ? ((8*q - 1 + s) & 255) : ((248 - 8*q + (s - 10)) & 255);
}

// ---------------- prep: mod_depth, pm, spectral line table ----------------
__global__ __launch_bounds__(256) void k_prep(const float* __restrict__ b1,
    const float* __restrict__ W2, const float* __restrict__ b2,
    const float* __restrict__ W3, const float* __restrict__ b3,
    const float* __restrict__ hp, const float* __restrict__ fw,
    float* __restrict__ pm_out, int* __restrict__ hidx, float* __restrict__ amp) {
  __shared__ float red[256];
  __shared__ float s_md, s_pm;
  int t = threadIdx.x;
  if (t == 0) {
    float h1[32], h2v[16];
    for (int i=0;i<32;i++){ float z = b1[i]; h1[i] = z > 0.f ? z : 0.f; }
    for (int o=0;o<16;o++){ float acc = b2[o];
      for (int i=0;i<32;i++) acc += h1[i]*W2[i*16+o];
      h2v[o] = acc > 0.f ? acc : 0.f; }
    float md = b3[1];
    for (int i=0;i<16;i++) md += h2v[i]*W3[i*8+1];
    s_md = md;
  }
  __syncthreads();
  float md = s_md;
  float partial = 0.f;
  for (int tt = t; tt < 65537; tt += 256) {
    int ci = (tt * 8) / 65537;
    float cs = hp[ci*4+0] + hp[ci*4+1] + hp[ci*4+2] + hp[ci*4+3];
    float ang = (6.2831853071795864769f * (float)tt) / 65537.0f;
    partial += cs * (1.f + md * sinf(ang));
  }
  red[t] = partial;
  __syncthreads();
  for (int s = 128; s > 0; s >>= 1) { if (t < s) red[t] += red[t+s]; __syncthreads(); }
  if (t == 0) { s_pm = red[0] / (65537.0f * 4.0f); pm_out[0] = s_pm; }
  __syncthreads();
  if (t < 40) {
    const double SPECF[8] = {7.83, 528.0, 396.0, 2.5, 14.1, 432.0, 6.0, 30.0};
    int j = t / 5, mi = t % 5;
    double mult = (double)(mi + 1);
    double hf = SPECF[j] * mult;
    double ratio = hf * (131072.0 / 22050.0);
    hidx[t] = (int)floor(ratio + 0.5);
    amp[t] = (float)((double)fw[j] * pow(mult, -1.2) * (1.0 + (double)s_pm));
  }
}

// ---------------- gain curve -> transposed layout gain_t[c*257 + k1] ------
__global__ __launch_bounds__(256) void k_gain(float* __restrict__ gain_t,
    const float* __restrict__ bw, const int* __restrict__ hidx,
    const float* __restrict__ amp) {
  int i = blockIdx.x*256 + threadIdx.x;
  if (i >= 65537) return;
  float f = (float)((double)i * (22050.0/131072.0));
  float g = 1.0f;
  constexpr double LO[6] = {1,4,8,13,30,100};
  constexpr double HI[6] = {4,8,13,30,100,200};
  #pragma unroll
  for (int k = 0; k < 6; ++k) {
    float center = (float)(0.5*(LO[k]+HI[k]));
    float sig    = (float)(0.25*(HI[k]-LO[k]));
    float dm = (f - center)/sig;
    float mask = expf(-0.5f*dm*dm);
    if (f < (float)LO[k] || f > (float)HI[k]) mask = 0.f;
    float ang = (float)(6.283185307179586*0.5*(LO[k]+HI[k])) * (float)i / 22050.0f;
    g *= 1.0f + mask * bw[k] * (1.0f + 0.2f*sinf(ang));
  }
  for (int l = 0; l < 40; ++l) {
    int d = i - hidx[l];
    if (d >= -15 && d <= 15) {
      float dd = (float)d * 0.2f;
      g *= 1.0f + amp[l] * expf(-0.5f*dd*dd);
    }
  }
  int c = i & 255, k1 = i >> 8;        // i == c + 256*k1; i=65536 -> (0,256)
  gain_t[c*257 + k1] = g;
}

// ---------------- forward pass 1: pack + column FFT + 4-step twiddle ------
__global__ __launch_bounds__(256) void k_fwd1(const float* __restrict__ x,
                                              h2* __restrict__ A, int s0) {
  __shared__ float sre[4096], sim[4096];
  int b = blockIdx.x; int sl = b >> 4; int g = b & 15;
  int t = threadIdx.x & 15, r = threadIdx.x >> 4;
  int n1 = g*16 + t;
  const float* xb = x + (size_t)(s0 + sl) * L_SIG;
  c32 v[16];
  #pragma unroll
  for (int j = 0; j < 16; ++j) {
    int n = n1 + 256*r + 4096*j;
    c32 z = mkc(0.f, 0.f);
    if (n < 32768)       { z.x = xb[2*n]; z.y = xb[2*n+1]; }
    else if (n == 32768) { z.x = xb[65536]; }
    v[j] = z;
  }
  fft256_team<-1>(v, r, t, sre, sim);
  float a0 = -(2.0f*PI_F/65536.0f) * (float)(n1 * r);
  float a1 = -(2.0f*PI_F/4096.0f)  * (float)n1;
  c32 wb, wst;
  __sincosf(a0, &wb.y, &wb.x);
  __sincosf(a1, &wst.y, &wst.x);
  #pragma unroll
  for (int j = 0; j < 16; ++j) { v[j] = cmul(v[j], wb); wb = cmul(wb, wst); }
  __syncthreads();
  #pragma unroll
  for (int j = 0; j < 16; ++j) {
    int idx = (r + 16*j)*16 + t;
    sre[idx] = v[j].x; sim[idx] = v[j].y;
  }
  __syncthreads();
  h2* Ab = A + (size_t)sl * NH;
  int u = threadIdx.x & 15, k2b = threadIdx.x >> 4;
  #pragma unroll
  for (int m = 0; m < 16; ++m) {
    int k2 = k2b + 16*m;
    Ab[(size_t)k2*256 + g*16 + u] = c2h(mkc(sre[k2*16 + u], sim[k2*16 + u]));
  }
}

// ---------------- fused: row FFT + unpack/gain/smooth/repack + inv col FFT
// Block q owns k2 columns [8q,8q+8) + mirrors + halo (20 slots). 320 threads
// = 20 teams of 16, one FFT round each direction. All index math carried
// from the correctness-verified R2 kernel.
__global__ __launch_bounds__(320) void k_fused(const h2* __restrict__ A,
    h2* __restrict__ Bp, const float* __restrict__ gain_t) {
  __shared__ h2     ZC[20*ZSTR];      // 21120 B
  __shared__ __half MAG[20*ZSTR];     // 10560 B
  __shared__ int    colslot[256];     // 1024 B
  int b = blockIdx.x; int sl = b >> 4; int q = b & 15;
  int tid = threadIdx.x;
  int team = tid >> 4, r = tid & 15;
  const h2* Ab = A + (size_t)sl * NH;
  h2* Bb = Bp + (size_t)sl * NH;

  if (tid == 0) {   // descending: own slots win over dup/mirror slots
    for (int s = 19; s >= 0; --s) colslot[colof(q, s)] = s;
  }
  #pragma unroll
  for (int m = 0; m < 4; ++m) {      // stage 20 columns, float4-coalesced
    int f = tid + 320*m;
    int cs = f >> 6, i = f & 63;
    float4 z = *(const float4*)&Ab[(size_t)colof(q, cs)*256 + 4*i];
    *(float4*)&ZC[cs*ZSTR + 4*i] = z;
  }
  __syncthreads();

  // ---- forward 256-pt FFT over n1, one round, 20 teams ------------------
  {
    h2* row = ZC + team*ZSTR;
    c32 v[16];
    #pragma unroll
    for (int j = 0; j < 16; ++j) v[j] = h2c(row[r + 16*j]);
    fft16<-1>(v);
    float ang = -(2.0f*PI_F/256.0f) * (float)r;
    c32 st; __sincosf(ang, &st.y, &st.x);
    c32 w = st;
    #pragma unroll
    for (int c = 1; c < 16; ++c) { v[c] = cmul(v[c], w); w = cmul(w, st); }
    __syncthreads();
    #pragma unroll
    for (int c = 0; c < 16; ++c) row[c*16 + r] = c2h(v[c]);
    __syncthreads();
    #pragma unroll
    for (int a = 0; a < 16; ++a) v[a] = h2c(row[r*16 + a]);
    fft16<-1>(v);
    __syncthreads();
    #pragma unroll
    for (int j = 0; j < 16; ++j) row[r + 16*j] = c2h(v[j]);   // Z[k1]
  }
  __syncthreads();

  // ---- phase 1: gain-scaled magnitudes, mirror-paired (1 sincosf/pair) --
  for (int p = tid; p < 2560; p += 320) {
    int s = p >> 8, k1 = p & 255;
    int c = colof(q, s);
    int ms = 19 - s;
    bool c0 = (c == 0);                       // q==0, s==1 only
    int mzi = c0 ? (256 - k1) : (255 - k1);   // mirror k1-index (may be 256)
    int mz = mzi & 255;
    int k = c + 256*k1;
    c32 zk = h2c(ZC[s*ZSTR + k1]);
    c32 zb = h2c(ZC[ms*ZSTR + mz]);
    float sw, cw; __sincosf(-(PI_F/65536.0f)*(float)k, &sw, &cw);
    c32 Aa = mkc(0.5f*(zk.x+zb.x), 0.5f*(zk.y-zb.y));
    c32 Bm = mkc(0.5f*(zk.x-zb.x), 0.5f*(zk.y+zb.y));
    c32 XL = cadd(Aa, cmul(mkc(sw,-cw), Bm));                 // -i*W^k
    float gL = gain_t[c*257 + k1];
    MAG[s*ZSTR + k1] = __float2half(gL * sqrtf(XL.x*XL.x + XL.y*XL.y));
    c32 Aa2 = mkc(0.5f*(zb.x+zk.x), 0.5f*(zb.y-zk.y));
    c32 Bm2 = mkc(0.5f*(zb.x-zk.x), 0.5f*(zb.y+zk.y));
    c32 XH = cadd(Aa2, cmul(mkc(sw, cw), Bm2));               // -i*W^(N-k)=i*conj(W^k)
    float gH = gain_t[((256-c)&255)*257 + mzi];
    float mH = gH * sqrtf(XH.x*XH.x + XH.y*XH.y);
    MAG[ms*ZSTR + mzi] = __float2half(mH);
    if (c0 && k1 == 0) MAG[s*ZSTR + 256] = __float2half(mH);  // pseudo bin 65536 @ own slot
  }
  __syncthreads();

  // ---- phase 2: smooth + repack, in place on ZC (1 sincosf/pair) --------
  const float invN = 1.0f/65536.0f;
  for (int p = tid; p < 2048; p += 320) {
    int l = p >> 8, k1 = p & 255;
    int cL = 8*q + l;
    bool sp0 = (cL == 0);
    if (sp0 && k1 > 128) continue;
    int sL = 1 + l;
    int sHw = sp0 ? sL : (19 - sL);
    int sHr = sp0 ? 18 : sHw;
    int mI  = sp0 ? (256 - k1) : (255 - k1);
    int mz  = mI & 255;
    int k = cL + 256*k1;
    int K = 65536 - k;
    c32 zL = h2c(ZC[sL*ZSTR + k1]);
    c32 zH = h2c(ZC[sHr*ZSTR + mz]);
    float gk = gain_t[cL*257 + k1];
    float gK = gain_t[((256-cL)&255)*257 + mI];
    float sw, cw; __sincosf(-(PI_F/65536.0f)*(float)k, &sw, &cw);
    c32 Aa = mkc(0.5f*(zL.x+zH.x), 0.5f*(zL.y-zH.y));
    c32 Bm = mkc(0.5f*(zL.x-zH.x), 0.5f*(zL.y+zH.y));
    c32 XgL = cadd(Aa, cmul(mkc(sw,-cw), Bm)); XgL.x *= gk; XgL.y *= gk;
    c32 Aa2 = mkc(0.5f*(zH.x+zL.x), 0.5f*(zH.y-zL.y));
    c32 Bm2 = mkc(0.5f*(zH.x-zL.x), 0.5f*(zH.y+zL.y));
    c32 XgH = cadd(Aa2, cmul(mkc(sw, cw), Bm2)); XgH.x *= gK; XgH.y *= gK;
    float mL = sqrtf(XgL.x*XgL.x + XgL.y*XgL.y);
    float mH = sqrtf(XgH.x*XgH.x + XgH.y*XgH.y);
    float msL = mL, msH = mH;
    if (k != 0) {
      int km = k-1, kp = k+1;
      msL = 0.7f*mL + 0.15f*(__half2float(MAG[colslot[km & 255]*ZSTR + (km >> 8)])
                           + __half2float(MAG[colslot[kp & 255]*ZSTR + (kp >> 8)]));
    }
    if (K != 65536) {
      int Km = K-1, Kp = K+1;
      msH = 0.7f*mH + 0.15f*(__half2float(MAG[colslot[Km & 255]*ZSTR + (Km >> 8)])
                           + __half2float(MAG[colslot[Kp & 255]*ZSTR + (Kp >> 8)]));
    }
    c32 XcL = (mL > 0.f) ? mkc(XgL.x*(msL/mL), XgL.y*(msL/mL)) : mkc(msL, 0.f);
    c32 XcH = (mH > 0.f) ? mkc(XgH.x*(msH/mH), XgH.y*(msH/mH)) : mkc(msH, 0.f);
    c32 E = mkc(0.5f*(XcL.x + XcH.x), 0.5f*(XcL.y - XcH.y));
    c32 D = mkc(0.5f*(XcL.x - XcH.x), 0.5f*(XcL.y + XcH.y));
    c32 O = cmul(mkc(cw, -sw), D);                            // conj(W^k)
    ZC[sL*ZSTR + k1] = c2h(mkc((E.x - O.y)*invN, (E.y + O.x)*invN));
    if (!(sp0 && k1 == 0))
      ZC[sHw*ZSTR + mz] = c2h(mkc((E.x + O.y)*invN, (O.x - E.y)*invN));
  }
  if (q == 15) {                         // column 128 self-pair
    for (int k1 = tid; k1 < 128; k1 += 320) {
      int mz = 255 - k1;
      int k = 128 + 256*k1;
      int K = 65536 - k;
      c32 zL = h2c(ZC[9*ZSTR + k1]);
      c32 zH = h2c(ZC[10*ZSTR + mz]);    // dup col-128 (read-only)
      float gk = gain_t[128*257 + k1];
      float gK = gain_t[128*257 + mz];
      float sw, cw; __sincosf(-(PI_F/65536.0f)*(float)k, &sw, &cw);
      c32 Aa = mkc(0.5f*(zL.x+zH.x), 0.5f*(zL.y-zH.y));
      c32 Bm = mkc(0.5f*(zL.x-zH.x), 0.5f*(zL.y+zH.y));
      c32 XgL = cadd(Aa, cmul(mkc(sw,-cw), Bm)); XgL.x *= gk; XgL.y *= gk;
      c32 Aa2 = mkc(0.5f*(zH.x+zL.x), 0.5f*(zH.y-zL.y));
      c32 Bm2 = mkc(0.5f*(zH.x-zL.x), 0.5f*(zH.y+zL.y));
      c32 XgH = cadd(Aa2, cmul(mkc(sw, cw), Bm2)); XgH.x *= gK; XgH.y *= gK;
      float mL = sqrtf(XgL.x*XgL.x + XgL.y*XgL.y);
      float mH = sqrtf(XgH.x*XgH.x + XgH.y*XgH.y);
      int km = k-1, kp = k+1, Km = K-1, Kp = K+1;
      float msL = 0.7f*mL + 0.15f*(__half2float(MAG[colslot[km & 255]*ZSTR + (km >> 8)])
                                 + __half2float(MAG[colslot[kp & 255]*ZSTR + (kp >> 8)]));
      float msH = 0.7f*mH + 0.15f*(__half2float(MAG[colslot[Km & 255]*ZSTR + (Km >> 8)])
                                 + __half2float(MAG[colslot[Kp & 255]*ZSTR + (Kp >> 8)]));
      c32 XcL = (mL > 0.f) ? mkc(XgL.x*(msL/mL), XgL.y*(msL/mL)) : mkc(msL, 0.f);
      c32 XcH = (mH > 0.f) ? mkc(XgH.x*(msH/mH), XgH.y*(msH/mH)) : mkc(msH, 0.f);
      c32 E = mkc(0.5f*(XcL.x + XcH.x), 0.5f*(XcL.y - XcH.y));
      c32 D = mkc(0.5f*(XcL.x - XcH.x), 0.5f*(XcL.y + XcH.y));
      c32 O = cmul(mkc(cw, -sw), D);
      ZC[9*ZSTR + k1] = c2h(mkc((E.x - O.y)*invN, (E.y + O.x)*invN));
      ZC[9*ZSTR + mz] = c2h(mkc((E.x + O.y)*invN, (O.x - E.y)*invN));
    }
  }
  __syncthreads();

  // ---- inverse first-stage FFT over k1 + 4-step twiddle + B' write ------
  int ncols = (q == 0) ? 15 : ((q == 15) ? 17 : 16);
  {
    bool act = team < ncols;
    int slot = act ? ((team < 8) ? (1 + team) : ((team < 16) ? (3 + team) : 9)) : 0;
    int a = colof(q, slot);
    h2* row = ZC + slot*ZSTR;
    c32 v[16];
    if (act) {
      #pragma unroll
      for (int j = 0; j < 16; ++j) v[j] = h2c(row[r + 16*j]);
      fft16<1>(v);
      float ang = (2.0f*PI_F/256.0f) * (float)r;
      c32 st; __sincosf(ang, &st.y, &st.x);
      c32 w = st;
      #pragma unroll
      for (int c = 1; c < 16; ++c) { v[c] = cmul(v[c], w); w = cmul(w, st); }
    }
    __syncthreads();
    if (act) {
      #pragma unroll
      for (int c = 0; c < 16; ++c) row[c*16 + r] = c2h(v[c]);
    }
    __syncthreads();
    if (act) {
      #pragma unroll
      for (int a2 = 0; a2 < 16; ++a2) v[a2] = h2c(row[r*16 + a2]);
      fft16<1>(v);
      float a0 = (2.0f*PI_F/65536.0f) * (float)(a * r);
      float a1 = (2.0f*PI_F/4096.0f)  * (float)a;
      c32 wb, wst;
      __sincosf(a0, &wb.y, &wb.x);
      __sincosf(a1, &wst.y, &wst.x);
      #pragma unroll
      for (int j = 0; j < 16; ++j) {
        c32 o = cmul(v[j], wb); wb = cmul(wb, wst);
        Bb[(size_t)a*256 + r + 16*j] = c2h(o);   // B'[a][m2], contiguous per column
      }
    }
  }
}

// ---------------- inverse pass 2: reads B'[a*256+m2], FFT over a ----------
__global__ __launch_bounds__(256) void k_inv2t(const h2* __restrict__ Bp,
                                               float* __restrict__ out, int s0) {
  __shared__ float sre[4096], sim[4096];   // stg (16 KB) aliases sre
  h2* stg = (h2*)sre;                      // stg[a*16 + mo]
  int b = blockIdx.x; int sl = b >> 4; int g = b & 15;
  int tid = threadIdx.x;
  int t = tid & 15, r = tid >> 4;
  const h2* Bb = Bp + (size_t)sl * NH;
  #pragma unroll
  for (int m = 0; m < 4; ++m) {
    int idx = tid + 256*m;                 // [0,1024)
    int a = idx >> 2, mq = idx & 3;
    float4 z = *(const float4*)&Bb[(size_t)a*256 + 16*g + 4*mq];
    *(float4*)&stg[a*16 + 4*mq] = z;
  }
  __syncthreads();
  c32 v[16];
  #pragma unroll
  for (int j = 0; j < 16; ++j) v[j] = h2c(stg[(r + 16*j)*16 + t]);
  fft256_team<1>(v, r, t, sre, sim);       // stg dead after fragments read
  float* yb = out + (size_t)(s0 + sl) * L_SIG;
  int m2 = g*16 + t;
  #pragma unroll
  for (int j = 0; j < 16; ++j) {
    int m1 = r + 16*j;
    if (m1 <= 127) {
      int m = m2 + 256*m1;
      yb[2*m]   = v[j].x;
      yb[2*m+1] = v[j].y;
    } else if (m1 == 128 && m2 == 0) {
      yb[65536] = v[j].x;
    }
  }
}

// --------------------------------------------------------------------------
extern "C" void kernel_launch(void* const* d_in, const int* in_sizes, int n_in,
                              void* d_out, int out_size, void* d_ws, size_t ws_size,
                              hipStream_t stream) {
  const float* x  = (const float*)d_in[0];
  const float* bw = (const float*)d_in[1];
  const float* fw = (const float*)d_in[2];
  const float* hp = (const float*)d_in[3];
  // d_in[4] = W1: mathematically unused (tn==0 at the only sampled row)
  const float* b1 = (const float*)d_in[5];
  const float* W2 = (const float*)d_in[6];
  const float* b2 = (const float*)d_in[7];
  const float* W3 = (const float*)d_in[8];
  const float* b3 = (const float*)d_in[9];
  float* out = (float*)d_out;
  char* ws = (char*)d_ws;

  const size_t perSig = (size_t)NH * sizeof(h2);              // 256 KiB / signal / buffer
  const size_t tail   = (size_t)66048 * sizeof(float) + 1024; // gain_t + scalars
  size_t cap = (ws_size > tail) ? (ws_size - tail) / (2*perSig) : 1;
  int chunk = (cap >= (size_t)NSIG) ? NSIG : (cap < 1 ? 1 : (int)cap);

  h2*    A      = (h2*)ws;
  h2*    Bb     = (h2*)(ws + (size_t)chunk*perSig);
  float* gain_t = (float*)(ws + 2*(size_t)chunk*perSig);
  float* pm     = gain_t + 66048;
  int*   hidx   = (int*)(pm + 1);
  float* amp    = (float*)(hidx + 40);

  k_prep<<<1, 256, 0, stream>>>(b1, W2, b2, W3, b3, hp, fw, pm, hidx, amp);
  k_gain<<<257, 256, 0, stream>>>(gain_t, bw, hidx, amp);

  for (int s0 = 0; s0 < NSIG; s0 += chunk) {
    int S = (NSIG - s0 < chunk) ? (NSIG - s0) : chunk;
    k_fwd1 <<<S*16, 256, 0, stream>>>(x, A, s0);
    k_fused<<<S*16, 320, 0, stream>>>(A, Bb, gain_t);
    k_inv2t<<<S*16, 256, 0, stream>>>(Bb, out, s0);
  }
}